// Round 1
// baseline (206.285 us; speedup 1.0000x reference)
//
#include <hip/hip_runtime.h>

#define L_SEQ 8192
#define DIMN  2048
#define CHUNK 64
#define NCHUNK (L_SEQ / CHUNK)   // 128

typedef float  f32x4  __attribute__((ext_vector_type(4)));
typedef __bf16 bf16x8 __attribute__((ext_vector_type(8)));

__device__ __forceinline__ unsigned short f2bf(float f) {
    unsigned int u = __float_as_uint(f);
    u += 0x7fffu + ((u >> 16) & 1u);          // round-to-nearest-even
    return (unsigned short)(u >> 16);
}

__device__ __forceinline__ float sigmoidf_(float v) {
    return 1.0f / (1.0f + __expf(-v));
}

// ---- Stage 1 (fused): local chunk scans (blocks 0..255) + W fp32->bf16 (blocks 256..4351)
__global__ void stage1(const float* __restrict__ x, const float* __restrict__ fp,
                       const float* __restrict__ W,
                       float* __restrict__ carry, unsigned short* __restrict__ Wb) {
    int b = blockIdx.x;
    if (b < 256) {
        int cg = b & 1;                       // channel group (1024 ch each)
        int c  = b >> 1;                      // chunk
        int d4 = cg * 256 + threadIdx.x;      // float4 channel index
        float4 f4 = ((const float4*)fp)[d4];
        float fa = sigmoidf_(f4.x), fb = sigmoidf_(f4.y),
              fc = sigmoidf_(f4.z), fd = sigmoidf_(f4.w);
        float ga = 1.f - fa, gb = 1.f - fb, gc = 1.f - fc, gd = 1.f - fd;
        float ha = 0.f, hb = 0.f, hc = 0.f, hd = 0.f;
        const float4* xp = (const float4*)(x + (size_t)c * CHUNK * DIMN) + d4;
#pragma unroll 8
        for (int t = 0; t < CHUNK; ++t) {
            float4 v = xp[(size_t)t * (DIMN / 4)];
            ha = fmaf(fa, ha, ga * v.x);
            hb = fmaf(fb, hb, gb * v.y);
            hc = fmaf(fc, hc, gc * v.z);
            hd = fmaf(fd, hd, gd * v.w);
        }
        ((float4*)(carry + (size_t)c * DIMN))[d4] = (float4){ha, hb, hc, hd};
    } else {
        int i = (b - 256) * 256 + threadIdx.x;     // float4 index into W
        float4 v = ((const float4*)W)[i];
        ushort4 o;
        o.x = f2bf(v.x); o.y = f2bf(v.y); o.z = f2bf(v.z); o.w = f2bf(v.w);
        ((ushort4*)Wb)[i] = o;
    }
}

// ---- Stage 2: sequential prefix over chunks, all carries held in VGPRs ----
__global__ __launch_bounds__(64) void carry_prefix(const float* __restrict__ fp,
                                                   const float* __restrict__ xml,
                                                   float* __restrict__ carry) {
    int d = blockIdx.x * 64 + threadIdx.x;        // one channel per lane
    float f = sigmoidf_(fp[d]);
    float fC = f;                                  // f^64 via 6 squarings
    fC *= fC; fC *= fC; fC *= fC; fC *= fC; fC *= fC; fC *= fC;
    float v[NCHUNK];
#pragma unroll
    for (int c = 0; c < NCHUNK; ++c) v[c] = carry[(size_t)c * DIMN + d];
    float h = xml[d];
#pragma unroll
    for (int c = 0; c < NCHUNK; ++c) {
        carry[(size_t)c * DIMN + d] = h;           // h_in for chunk c
        h = fmaf(fC, h, v[c]);
    }
}

// ---- Stage 3: re-scan with correct h_in, emit x_mix as bf16 ----
__global__ void scan_apply(const float* __restrict__ x, const float* __restrict__ fp,
                           const float* __restrict__ carry, unsigned short* __restrict__ xmix) {
    int b = blockIdx.x;
    int cg = b & 1;
    int c  = b >> 1;
    int d4 = cg * 256 + threadIdx.x;
    float4 f4 = ((const float4*)fp)[d4];
    float fa = sigmoidf_(f4.x), fb = sigmoidf_(f4.y),
          fc = sigmoidf_(f4.z), fd = sigmoidf_(f4.w);
    float ga = 1.f - fa, gb = 1.f - fb, gc = 1.f - fc, gd = 1.f - fd;
    float4 h0 = ((const float4*)(carry + (size_t)c * DIMN))[d4];
    float ha = h0.x, hb = h0.y, hc = h0.z, hd = h0.w;
    const float4* xp = (const float4*)(x + (size_t)c * CHUNK * DIMN) + d4;
    ushort4* op = (ushort4*)(xmix + (size_t)c * CHUNK * DIMN) + d4;
#pragma unroll 8
    for (int t = 0; t < CHUNK; ++t) {
        float4 v = xp[(size_t)t * (DIMN / 4)];
        ha = fmaf(fa, ha, ga * v.x);
        hb = fmaf(fb, hb, gb * v.y);
        hc = fmaf(fc, hc, gc * v.z);
        hd = fmaf(fd, hd, gd * v.w);
        ushort4 o; o.x = f2bf(ha); o.y = f2bf(hb); o.z = f2bf(hc); o.w = f2bf(hd);
        op[(size_t)t * (DIMN / 4)] = o;
    }
}

// ---- GEMM: C[M][N] = A[M][K] * B[N][K]^T, bf16 in / fp32 out ----
// 256x256 tile, BK=64, 8 waves (2M x 4N), per-wave 128x64 output = acc[2][4][4].
// 8-phase schedule (T3+T4+T5): per K-tile 4 phases, each
//   {8 or 4 ds_read_b128 || stage one 16KB unit (2 global_load_lds)}
//   -> barrier -> setprio(1) 16 MFMA setprio(0) -> [vmcnt(8) at P2/P4] -> barrier.
// LDS = 2 buffers x 4 contiguous 16KB sub-arrays [Aklo,Bklo,Akhi,Bkhi] (128 KB):
// global_load_lds needs lane-linear dests, so staging units are K-column halves
// stored as separate sub-arrays; swizzle slot ^= (row>>1)&3 within each (2-way
// bank aliasing = free). Phase order kk-major => klo consumed after P2, khi
// after P4 => staging P1:Akhi(T+1) P2:Bkhi(T+1) P3:Aklo(T+2) P4:Bklo(T+2) is
// WAR-safe; steady-state vmcnt(8) (4 units in flight), tail vmcnt(4)/vmcnt(0).
#define GLD16(gp, lp) __builtin_amdgcn_global_load_lds( \
        (const __attribute__((address_space(1))) void*)(gp), \
        (__attribute__((address_space(3))) void*)(lp), 16, 0, 0)
#define WAITV(N) asm volatile("s_waitcnt vmcnt(" #N ")" ::: "memory")

__global__ __launch_bounds__(512, 2) void gemm_bt(
        const unsigned short* __restrict__ A,
        const unsigned short* __restrict__ B,
        float* __restrict__ C) {
    constexpr int N_ = DIMN, K_ = DIMN;
    constexpr int NT = K_ / 64;                    // 32 K-tiles
    __shared__ __align__(16) unsigned short lds[2 * 32768];   // 128 KB

    const int tid  = threadIdx.x;
    const int wave = tid >> 6;
    const int lane = tid & 63;
    const int quad = lane >> 4;
    const int l16  = lane & 15;
    const int wm = wave >> 2;                      // 0..1
    const int wn = wave & 3;                       // 0..3
    const int tm = blockIdx.x, tn = blockIdx.y;

    // Staging constants (identical for A and B units: 256 rows x 4 slots x 16B).
    const int i0 = tid, i1 = 512 + tid;
    const int r0 = i0 >> 2, s0 = i0 & 3;
    const int r1 = i1 >> 2, s1 = i1 & 3;
    const size_t src0 = (size_t)r0 * K_ + (size_t)((s0 ^ ((r0 >> 1) & 3)) * 8);
    const size_t src1 = (size_t)r1 * K_ + (size_t)((s1 ^ ((r1 >> 1) & 3)) * 8);
    const int dst0 = tid * 8;                      // lane-linear LDS dest (ushort)
    const int dst1 = 4096 + tid * 8;

    const unsigned short* aBase = A + (size_t)(tm * 256) * K_;
    const unsigned short* bBase = B + (size_t)(tn * 256) * K_;

    // Fragment LDS offsets (within a 256x32 sub-array), swizzled.
    int offA[2][4], offB[4];
#pragma unroll
    for (int ih = 0; ih < 2; ++ih)
#pragma unroll
        for (int i = 0; i < 4; ++i) {
            int r = wm * 128 + ih * 64 + i * 16 + l16;
            offA[ih][i] = r * 32 + ((quad ^ ((r >> 1) & 3)) << 3);
        }
#pragma unroll
    for (int j = 0; j < 4; ++j) {
        int r = wn * 64 + j * 16 + l16;
        offB[j] = r * 32 + ((quad ^ ((r >> 1) & 3)) << 3);
    }

    f32x4 acc[2][4][4];
#pragma unroll
    for (int ih = 0; ih < 2; ++ih)
#pragma unroll
        for (int i = 0; i < 4; ++i)
#pragma unroll
            for (int j = 0; j < 4; ++j)
                acc[ih][i][j] = (f32x4){0.f, 0.f, 0.f, 0.f};

    // STAGE(ab, h, b, t): ab 0=A 1=B; h 0=klo 1=khi; b = LDS buffer; t = K-tile.
#define STAGE(ab, h, b, t) do { \
        const unsigned short* _g = ((ab) ? bBase : aBase) + (size_t)(t) * 64 + (h) * 32; \
        unsigned short* _l = lds + (b) * 32768 + ((h) * 2 + (ab)) * 8192; \
        GLD16(_g + src0, _l + dst0); \
        GLD16(_g + src1, _l + dst1); \
    } while (0)

    // Prologue: tile0 fully + tile1 klo. vmcnt(8) -> Aklo(0),Bklo(0) resident.
    STAGE(0, 0, 0, 0);   // Aklo(0)
    STAGE(1, 0, 0, 0);   // Bklo(0)
    STAGE(0, 1, 0, 0);   // Akhi(0)
    STAGE(1, 1, 0, 0);   // Bkhi(0)
    STAGE(0, 0, 1, 1);   // Aklo(1)
    STAGE(1, 0, 1, 1);   // Bklo(1)
    WAITV(8);
    __builtin_amdgcn_s_barrier();
    __builtin_amdgcn_sched_barrier(0);

    bf16x8 bg[4];
    for (int T = 0; T < NT; ++T) {
        const int buf = T & 1;
        const unsigned short* Aklo = lds + buf * 32768;
        const unsigned short* Bklo = Aklo + 8192;
        const unsigned short* Akhi = Aklo + 16384;
        const unsigned short* Bkhi = Aklo + 24576;
        bf16x8 af[4];

        // ---- P1: klo, ih0 (reads A rows wm*128+[0,64) + all B klo) ----
#pragma unroll
        for (int i = 0; i < 4; ++i) af[i] = *(const bf16x8*)(Aklo + offA[0][i]);
#pragma unroll
        for (int j = 0; j < 4; ++j) bg[j] = *(const bf16x8*)(Bklo + offB[j]);
        if (T + 1 < NT) STAGE(0, 1, buf ^ 1, T + 1);   // Akhi(T+1)
        __builtin_amdgcn_s_barrier();
        __builtin_amdgcn_s_setprio(1);
#pragma unroll
        for (int i = 0; i < 4; ++i)
#pragma unroll
            for (int j = 0; j < 4; ++j)
                acc[0][i][j] = __builtin_amdgcn_mfma_f32_16x16x32_bf16(af[i], bg[j], acc[0][i][j], 0, 0, 0);
        __builtin_amdgcn_s_setprio(0);
        __builtin_amdgcn_s_barrier();

        // ---- P2: klo, ih1 (bg reused) ----
#pragma unroll
        for (int i = 0; i < 4; ++i) af[i] = *(const bf16x8*)(Aklo + offA[1][i]);
        if (T + 1 < NT) STAGE(1, 1, buf ^ 1, T + 1);   // Bkhi(T+1)
        __builtin_amdgcn_s_barrier();
        __builtin_amdgcn_s_setprio(1);
#pragma unroll
        for (int i = 0; i < 4; ++i)
#pragma unroll
            for (int j = 0; j < 4; ++j)
                acc[1][i][j] = __builtin_amdgcn_mfma_f32_16x16x32_bf16(af[i], bg[j], acc[1][i][j], 0, 0, 0);
        __builtin_amdgcn_s_setprio(0);
        // site A: guard Akhi(T)/Bkhi(T) for P3 reads.
        if (T < NT - 1) { WAITV(8); } else { WAITV(0); }
        __builtin_amdgcn_s_barrier();
        __builtin_amdgcn_sched_barrier(0);

        // ---- P3: khi, ih0 ----
#pragma unroll
        for (int i = 0; i < 4; ++i) af[i] = *(const bf16x8*)(Akhi + offA[0][i]);
#pragma unroll
        for (int j = 0; j < 4; ++j) bg[j] = *(const bf16x8*)(Bkhi + offB[j]);
        if (T + 2 < NT) STAGE(0, 0, buf, T + 2);       // Aklo(T+2)
        __builtin_amdgcn_s_barrier();
        __builtin_amdgcn_s_setprio(1);
#pragma unroll
        for (int i = 0; i < 4; ++i)
#pragma unroll
            for (int j = 0; j < 4; ++j)
                acc[0][i][j] = __builtin_amdgcn_mfma_f32_16x16x32_bf16(af[i], bg[j], acc[0][i][j], 0, 0, 0);
        __builtin_amdgcn_s_setprio(0);
        __builtin_amdgcn_s_barrier();

        // ---- P4: khi, ih1 (bg reused) ----
#pragma unroll
        for (int i = 0; i < 4; ++i) af[i] = *(const bf16x8*)(Akhi + offA[1][i]);
        if (T + 2 < NT) STAGE(1, 0, buf, T + 2);       // Bklo(T+2)
        __builtin_amdgcn_s_barrier();
        __builtin_amdgcn_s_setprio(1);
#pragma unroll
        for (int i = 0; i < 4; ++i)
#pragma unroll
            for (int j = 0; j < 4; ++j)
                acc[1][i][j] = __builtin_amdgcn_mfma_f32_16x16x32_bf16(af[i], bg[j], acc[1][i][j], 0, 0, 0);
        __builtin_amdgcn_s_setprio(0);
        // site B: guard Aklo(T+1)/Bklo(T+1) for next group's P1 reads.
        if (T < NT - 2)      { WAITV(8); }
        else if (T == NT - 2) { WAITV(4); }
        __builtin_amdgcn_s_barrier();
        __builtin_amdgcn_sched_barrier(0);
    }
#undef STAGE

    // Epilogue: C/D layout col = lane&15, row = quad*4 + reg.
#pragma unroll
    for (int ih = 0; ih < 2; ++ih)
#pragma unroll
        for (int i = 0; i < 4; ++i)
#pragma unroll
            for (int j = 0; j < 4; ++j) {
                int col = tn * 256 + wn * 64 + j * 16 + l16;
#pragma unroll
                for (int r = 0; r < 4; ++r) {
                    int row = tm * 256 + wm * 128 + ih * 64 + i * 16 + quad * 4 + r;
                    C[(size_t)row * N_ + col] = acc[ih][i][j][r];
                }
            }
}

extern "C" void kernel_launch(void* const* d_in, const int* in_sizes, int n_in,
                              void* d_out, int out_size, void* d_ws, size_t ws_size,
                              hipStream_t stream) {
    const float* x   = (const float*)d_in[0];   // [L, D]
    const float* xml = (const float*)d_in[1];   // [D]
    const float* fp  = (const float*)d_in[2];   // [D]
    const float* W   = (const float*)d_in[3];   // [D, D]
    float* out = (float*)d_out;                 // [L, D] fp32

    unsigned short* xmix = (unsigned short*)d_ws;                                      // 32 MB
    unsigned short* Wb   = (unsigned short*)((char*)d_ws + (size_t)L_SEQ * DIMN * 2);  // 8 MB
    float* carry = (float*)((char*)d_ws + (size_t)L_SEQ * DIMN * 2 + (size_t)DIMN * DIMN * 2); // 1 MB

    stage1<<<256 + DIMN * DIMN / 4 / 256, 256, 0, stream>>>(x, fp, W, carry, Wb);
    carry_prefix<<<DIMN / 64, 64, 0, stream>>>(fp, xml, carry);
    scan_apply<<<256, 256, 0, stream>>>(x, fp, carry, xmix);
    gemm_bt<<<dim3(L_SEQ / 256, DIMN / 256), 512, 0, stream>>>(xmix, Wb, out);
}